// Round 5
// baseline (180.562 us; speedup 1.0000x reference)
//
#include <hip/hip_runtime.h>

#define N_TOK 2048
#define DMODEL 1024
#define NH 16
#define NKV 4
#define HDIM 64
#define SCALE_LOG2E 0.1803368801111204f  // (1/8) * log2(e)

typedef __attribute__((ext_vector_type(8))) short short8;
typedef __attribute__((ext_vector_type(4))) float f32x4;
typedef unsigned short u16;
typedef unsigned int u32;

__device__ __forceinline__ u16 f2bf(float x) {
    u32 u = __float_as_uint(x);
    u += 0x7FFF + ((u >> 16) & 1);   // round-to-nearest-even
    return (u16)(u >> 16);
}
__device__ __forceinline__ u32 pack2(float a, float b) {
    return (u32)f2bf(a) | ((u32)f2bf(b) << 16);
}

// ---------------------------------------------------------------------------
// prep: z=0..3 transpose W (K x NC) -> Wt (NC x K) bf16; z=4 convert x -> bf16
// ---------------------------------------------------------------------------
__global__ __launch_bounds__(256) void prep(
    const float* __restrict__ Wq, const float* __restrict__ Wk,
    const float* __restrict__ Wv, const float* __restrict__ Wo,
    const float* __restrict__ x,
    u16* __restrict__ Wqt, u16* __restrict__ Wkt, u16* __restrict__ Wvt,
    u16* __restrict__ Wot, u16* __restrict__ xb)
{
    const int z = blockIdx.z;
    const int t = threadIdx.x;
    if (z == 4) {
        size_t base = ((size_t)(blockIdx.y * 16 + blockIdx.x)) * 8192;
#pragma unroll
        for (int i = 0; i < 8; ++i) {
            float4 v = *(const float4*)(x + base + i * 1024 + t * 4);
            uint2 p; p.x = pack2(v.x, v.y); p.y = pack2(v.z, v.w);
            *(uint2*)(xb + base + i * 1024 + t * 4) = p;
        }
        return;
    }
    const float* W; u16* Wt; int NC;
    if      (z == 0) { W = Wq; Wt = Wqt; NC = 1024; }
    else if (z == 1) { W = Wk; Wt = Wkt; NC = 256; }
    else if (z == 2) { W = Wv; Wt = Wvt; NC = 256; }
    else             { W = Wo; Wt = Wot; NC = 1024; }
    const int n0 = blockIdx.x * 64;
    if (n0 >= NC) return;
    const int k0 = blockIdx.y * 64;
    __shared__ float T[64][68];
    const int row = t >> 2, cs = (t & 3) * 16;
#pragma unroll
    for (int i = 0; i < 4; ++i)
        *(float4*)&T[row][cs + i * 4] =
            *(const float4*)(W + (size_t)(k0 + row) * NC + n0 + cs + i * 4);
    __syncthreads();
    const int nl = t >> 2, ks = (t & 3) * 16;
    u32 pk[8];
#pragma unroll
    for (int i = 0; i < 8; ++i)
        pk[i] = pack2(T[ks + 2 * i][nl], T[ks + 2 * i + 1][nl]);
    u16* dst = Wt + (size_t)(n0 + nl) * DMODEL + k0 + ks;
    uint4 w0; w0.x = pk[0]; w0.y = pk[1]; w0.z = pk[2]; w0.w = pk[3];
    uint4 w1; w1.x = pk[4]; w1.y = pk[5]; w1.z = pk[6]; w1.w = pk[7];
    *(uint4*)(dst) = w0;
    *(uint4*)(dst + 8) = w1;
}

// ---------------------------------------------------------------------------
// QKV GEMM: tile 128x128, BK=32, 4 waves of 64x64 (m97 structure, 16 mfma/wave/iter).
// grid (16,12): by<8 -> Q (rope, x SCALE_LOG2E); 8,9 -> K (rope); 10,11 -> vT
// ---------------------------------------------------------------------------
__global__ __launch_bounds__(256, 2) void gemm_qkv(
    const u16* __restrict__ A,
    const u16* __restrict__ B0, const u16* __restrict__ B1, const u16* __restrict__ B2,
    u16* __restrict__ D0, u16* __restrict__ D1, u16* __restrict__ D2,
    const float* __restrict__ fc, const float* __restrict__ fs)
{
    __shared__ u16 As[128][40];
    __shared__ u16 Bs[128][40];
    const int t = threadIdx.x;
    const int m0 = blockIdx.x * 128;
    const int by = blockIdx.y;

    const u16* Bt; int nl0, ep;           // ep: 1 rope bf16, 2 vT
    u16* dbf; int dstride = 0; float epsc = 1.f;
    if (by < 8)       { Bt = B0; nl0 = by * 128;        dbf = D0; ep = 1; dstride = 1024;
                        epsc = SCALE_LOG2E; }
    else if (by < 10) { Bt = B1; nl0 = (by - 8) * 128;  dbf = D1; ep = 1; dstride = 256; }
    else              { Bt = B2; nl0 = (by - 10) * 128; dbf = D2; ep = 2; }

    const int w = t >> 6, lane = t & 63;
    const int quad = lane >> 4, l15 = lane & 15;
    const int wm = (w >> 1) * 64, wn = (w & 1) * 64;
    const int srow = t >> 1, sk = (t & 1) * 16;

    const u16* Ap = A + (size_t)(m0 + srow) * DMODEL + sk;
    const u16* Bp = Bt + (size_t)(nl0 + srow) * DMODEL + sk;

    f32x4 acc[4][4];
#pragma unroll
    for (int i = 0; i < 4; ++i)
#pragma unroll
        for (int j = 0; j < 4; ++j) acc[i][j] = {0.f, 0.f, 0.f, 0.f};

    uint4 ar0 = *(const uint4*)(Ap);
    uint4 ar1 = *(const uint4*)(Ap + 8);
    uint4 br0 = *(const uint4*)(Bp);
    uint4 br1 = *(const uint4*)(Bp + 8);

    for (int k0 = 0; k0 < DMODEL; k0 += 32) {
        __syncthreads();
        *(uint4*)&As[srow][sk]     = ar0;
        *(uint4*)&As[srow][sk + 8] = ar1;
        *(uint4*)&Bs[srow][sk]     = br0;
        *(uint4*)&Bs[srow][sk + 8] = br1;
        __syncthreads();
        if (k0 + 32 < DMODEL) {
            ar0 = *(const uint4*)(Ap + k0 + 32);
            ar1 = *(const uint4*)(Ap + k0 + 40);
            br0 = *(const uint4*)(Bp + k0 + 32);
            br1 = *(const uint4*)(Bp + k0 + 40);
        }
        short8 af[4], bf[4];
#pragma unroll
        for (int i = 0; i < 4; ++i)
            af[i] = *(const short8*)&As[wm + i * 16 + l15][quad * 8];
#pragma unroll
        for (int j = 0; j < 4; ++j)
            bf[j] = *(const short8*)&Bs[wn + j * 16 + l15][quad * 8];
#pragma unroll
        for (int i = 0; i < 4; ++i)
#pragma unroll
            for (int j = 0; j < 4; ++j)
                acc[i][j] = __builtin_amdgcn_mfma_f32_16x16x32_bf16(af[i], bf[j], acc[i][j], 0, 0, 0);
    }

#pragma unroll
    for (int i = 0; i < 4; ++i)
#pragma unroll
        for (int j = 0; j < 4; ++j) {
            const int cl = nl0 + wn + j * 16 + l15;
#pragma unroll
            for (int r4 = 0; r4 < 4; ++r4) {
                const int r = m0 + wm + i * 16 + quad * 4 + r4;
                float own = acc[i][j][r4];
                if (ep == 1) {
                    float other = __shfl_xor(own, 1, 64);
                    const int p = (cl & 63) >> 1;
                    const float c = fc[r * 32 + p] * epsc, s = fs[r * 32 + p] * epsc;
                    float outv = ((cl & 1) == 0) ? (own * c - other * s)
                                                 : (other * s + own * c);
                    dbf[(size_t)r * dstride + cl] = f2bf(outv);
                } else {
                    dbf[(size_t)cl * N_TOK + r] = f2bf(own);
                }
            }
        }
}

// ---------------------------------------------------------------------------
// Output GEMM: tile 64x128, BK=32, 4 waves of 32x64, fp32 out. grid (32,8).
// ---------------------------------------------------------------------------
__global__ __launch_bounds__(256, 2) void gemm_out(
    const u16* __restrict__ A, const u16* __restrict__ Bt, float* __restrict__ Dout)
{
    __shared__ u16 As[64][40];
    __shared__ u16 Bs[128][40];
    const int t = threadIdx.x;
    const int m0 = blockIdx.x * 64;
    const int nl0 = blockIdx.y * 128;

    const int w = t >> 6, lane = t & 63;
    const int quad = lane >> 4, l15 = lane & 15;
    const int wm = (w >> 1) * 32, wn = (w & 1) * 64;
    const int arow = t >> 2, acol = (t & 3) * 8;
    const int brow = t >> 1, bcol = (t & 1) * 16;

    const u16* Ap = A + (size_t)(m0 + arow) * DMODEL + acol;
    const u16* Bp = Bt + (size_t)(nl0 + brow) * DMODEL + bcol;

    f32x4 acc[2][4];
#pragma unroll
    for (int i = 0; i < 2; ++i)
#pragma unroll
        for (int j = 0; j < 4; ++j) acc[i][j] = {0.f, 0.f, 0.f, 0.f};

    uint4 ar  = *(const uint4*)(Ap);
    uint4 br0 = *(const uint4*)(Bp);
    uint4 br1 = *(const uint4*)(Bp + 8);

    for (int k0 = 0; k0 < DMODEL; k0 += 32) {
        __syncthreads();
        *(uint4*)&As[arow][acol]     = ar;
        *(uint4*)&Bs[brow][bcol]     = br0;
        *(uint4*)&Bs[brow][bcol + 8] = br1;
        __syncthreads();
        if (k0 + 32 < DMODEL) {
            ar  = *(const uint4*)(Ap + k0 + 32);
            br0 = *(const uint4*)(Bp + k0 + 32);
            br1 = *(const uint4*)(Bp + k0 + 40);
        }
        short8 af[2], bf[4];
#pragma unroll
        for (int i = 0; i < 2; ++i)
            af[i] = *(const short8*)&As[wm + i * 16 + l15][quad * 8];
#pragma unroll
        for (int j = 0; j < 4; ++j)
            bf[j] = *(const short8*)&Bs[wn + j * 16 + l15][quad * 8];
#pragma unroll
        for (int i = 0; i < 2; ++i)
#pragma unroll
            for (int j = 0; j < 4; ++j)
                acc[i][j] = __builtin_amdgcn_mfma_f32_16x16x32_bf16(af[i], bf[j], acc[i][j], 0, 0, 0);
    }

#pragma unroll
    for (int i = 0; i < 2; ++i)
#pragma unroll
        for (int j = 0; j < 4; ++j) {
            const int cl = nl0 + wn + j * 16 + l15;
#pragma unroll
            for (int r4 = 0; r4 < 4; ++r4) {
                const int r = m0 + wm + i * 16 + quad * 4 + r4;
                Dout[(size_t)r * 1024 + cl] = acc[i][j][r4];
            }
        }
}

// ---------------------------------------------------------------------------
// MFMA flash attention: 128 threads (2 waves), 64 q-rows/block (32 per wave),
// double-buffered K/V LDS staging (one barrier/iter), no-max softmax
// (scale*log2e folded into Q), wave-private P round-trip. Grid (32, 16).
// K/V B-frags registered once per iter and reused across both q-tiles.
// ---------------------------------------------------------------------------
__global__ __launch_bounds__(128) void attn(
    const u16* __restrict__ Qb, const u16* __restrict__ Kb,
    const u16* __restrict__ Vt, u16* __restrict__ Ob)
{
    __shared__ u16 Ks[2][64][72];   // [buf][key][d]
    __shared__ u16 Vs[2][64][72];   // [buf][d][key]
    __shared__ u16 Ps[2][32][68];   // [wave][qrow][key]

    const int t = threadIdx.x;
    const int n0 = blockIdx.x * 64;
    const int h = blockIdx.y, kvh = h >> 2;
    const int w = t >> 6, lane = t & 63;
    const int quad = lane >> 4, l15 = lane & 15;
    const int srow = t >> 1, shalf = (t & 1) * 32;   // staging: row, 32-elem half

    // Q A-frags: 2 q-tiles of 16 rows per wave
    short8 aq[2][2];
#pragma unroll
    for (int qt = 0; qt < 2; ++qt) {
        const u16* qp = Qb + (size_t)(n0 + w * 32 + qt * 16 + l15) * (NH * HDIM)
                        + h * HDIM + quad * 8;
        aq[qt][0] = *(const short8*)qp;
        aq[qt][1] = *(const short8*)(qp + 32);
    }

    const u16* kbase = Kb + (size_t)srow * (NKV * HDIM) + kvh * HDIM + shalf;
    const u16* vbase = Vt + (size_t)(kvh * HDIM + srow) * N_TOK + shalf;

    f32x4 o[2][4];
    float l_acc[2][4];
#pragma unroll
    for (int qt = 0; qt < 2; ++qt)
#pragma unroll
        for (int i = 0; i < 4; ++i) { o[qt][i] = {0.f, 0.f, 0.f, 0.f}; l_acc[qt][i] = 0.f; }

    // prologue: tile 0 -> buf 0 (each thread stages 64 B of K and of V)
    {
#pragma unroll
        for (int c = 0; c < 4; ++c) {
            *(uint4*)&Ks[0][srow][shalf + c * 8] = *(const uint4*)(kbase + c * 8);
            *(uint4*)&Vs[0][srow][shalf + c * 8] = *(const uint4*)(vbase + c * 8);
        }
    }
    __syncthreads();

    const int NT = N_TOK / 64;
    for (int kt = 0; kt < NT; ++kt) {
        const int cur = kt & 1, nxt = cur ^ 1;
        const int key0n = ((kt + 1) & (NT - 1)) * 64;
        uint4 kr[4], vr[4];
#pragma unroll
        for (int c = 0; c < 4; ++c) {
            kr[c] = *(const uint4*)(kbase + (size_t)key0n * (NKV * HDIM) + c * 8);
            vr[c] = *(const uint4*)(vbase + key0n + c * 8);
        }

        // ---- K B-frags (shared across q-tiles) ----
        short8 kb0[4], kb1[4];
#pragma unroll
        for (int nt = 0; nt < 4; ++nt) {
            kb0[nt] = *(const short8*)&Ks[cur][nt * 16 + l15][quad * 8];
            kb1[nt] = *(const short8*)&Ks[cur][nt * 16 + l15][quad * 8 + 32];
        }
        // ---- S = Q K^T : 2 q-tiles x 4 key-tiles ----
        f32x4 s[2][4];
#pragma unroll
        for (int qt = 0; qt < 2; ++qt)
#pragma unroll
            for (int nt = 0; nt < 4; ++nt) {
                f32x4 z = {0.f, 0.f, 0.f, 0.f};
                z = __builtin_amdgcn_mfma_f32_16x16x32_bf16(aq[qt][0], kb0[nt], z, 0, 0, 0);
                z = __builtin_amdgcn_mfma_f32_16x16x32_bf16(aq[qt][1], kb1[nt], z, 0, 0, 0);
                s[qt][nt] = z;
            }
        // ---- p = exp2(s); per-lane row-sums; P -> wave-private LDS ----
#pragma unroll
        for (int qt = 0; qt < 2; ++qt)
#pragma unroll
            for (int nt = 0; nt < 4; ++nt)
#pragma unroll
                for (int r = 0; r < 4; ++r) {
                    float p = __builtin_amdgcn_exp2f(s[qt][nt][r]);
                    l_acc[qt][r] += p;
                    Ps[w][qt * 16 + quad * 4 + r][nt * 16 + l15] = f2bf(p);
                }
        // ---- V B-frags (shared across q-tiles) ----
        short8 vb0[4], vb1[4];
#pragma unroll
        for (int dt = 0; dt < 4; ++dt) {
            vb0[dt] = *(const short8*)&Vs[cur][dt * 16 + l15][quad * 8];
            vb1[dt] = *(const short8*)&Vs[cur][dt * 16 + l15][quad * 8 + 32];
        }
        // ---- O += P V ----
#pragma unroll
        for (int qt = 0; qt < 2; ++qt) {
            const short8 ap0 = *(const short8*)&Ps[w][qt * 16 + l15][quad * 8];
            const short8 ap1 = *(const short8*)&Ps[w][qt * 16 + l15][quad * 8 + 32];
#pragma unroll
            for (int dt = 0; dt < 4; ++dt) {
                o[qt][dt] = __builtin_amdgcn_mfma_f32_16x16x32_bf16(ap0, vb0[dt], o[qt][dt], 0, 0, 0);
                o[qt][dt] = __builtin_amdgcn_mfma_f32_16x16x32_bf16(ap1, vb1[dt], o[qt][dt], 0, 0, 0);
            }
        }
        // ---- stage next tile; single barrier ----
#pragma unroll
        for (int c = 0; c < 4; ++c) {
            *(uint4*)&Ks[nxt][srow][shalf + c * 8] = kr[c];
            *(uint4*)&Vs[nxt][srow][shalf + c * 8] = vr[c];
        }
        __syncthreads();
    }

    // epilogue
#pragma unroll
    for (int qt = 0; qt < 2; ++qt) {
        float linv[4];
#pragma unroll
        for (int r = 0; r < 4; ++r) {
            float lv = l_acc[qt][r];
#pragma unroll
            for (int d = 1; d < 16; d <<= 1) lv += __shfl_xor(lv, d, 64);
            linv[r] = 1.f / lv;
        }
#pragma unroll
        for (int dt = 0; dt < 4; ++dt)
#pragma unroll
            for (int r = 0; r < 4; ++r) {
                const int qrow = n0 + w * 32 + qt * 16 + quad * 4 + r;
                const int col = h * HDIM + dt * 16 + l15;
                Ob[(size_t)qrow * (NH * HDIM) + col] = f2bf(o[qt][dt][r] * linv[r]);
            }
    }
}

// ---------------------------------------------------------------------------
extern "C" void kernel_launch(void* const* d_in, const int* in_sizes, int n_in,
                              void* d_out, int out_size, void* d_ws, size_t ws_size,
                              hipStream_t stream) {
    const float* x  = (const float*)d_in[0];
    const float* fc = (const float*)d_in[1];
    const float* fs = (const float*)d_in[2];
    const float* Wq = (const float*)d_in[3];
    const float* Wk = (const float*)d_in[4];
    const float* Wv = (const float*)d_in[5];
    const float* Wo = (const float*)d_in[6];
    float* out = (float*)d_out;

    u16* ws  = (u16*)d_ws;
    u16* xb  = ws;                         // 2048*1024
    u16* Wqt = xb  + (size_t)2048 * 1024;  // 1024*1024
    u16* Wkt = Wqt + (size_t)1024 * 1024;  // 256*1024
    u16* Wvt = Wkt + (size_t)256 * 1024;   // 256*1024
    u16* Wot = Wvt + (size_t)256 * 1024;   // 1024*1024
    u16* qb  = Wot + (size_t)1024 * 1024;  // 2048*1024
    u16* kb  = qb  + (size_t)2048 * 1024;  // 2048*256
    u16* vT  = kb  + (size_t)2048 * 256;   // 256*2048
    u16* aob = vT  + (size_t)256 * 2048;   // 2048*1024

    prep<<<dim3(16, 16, 5), dim3(256), 0, stream>>>(Wq, Wk, Wv, Wo, x,
                                                    Wqt, Wkt, Wvt, Wot, xb);
    gemm_qkv<<<dim3(16, 12), dim3(256), 0, stream>>>(xb, Wqt, Wkt, Wvt,
                                                     qb, kb, vT, fc, fs);
    attn<<<dim3(32, 16), dim3(128), 0, stream>>>(qb, kb, vT, aob);
    gemm_out<<<dim3(32, 8), dim3(256), 0, stream>>>(aob, Wot, out);
}

// Round 6
// 159.016 us; speedup vs baseline: 1.1355x; 1.1355x over previous
//
#include <hip/hip_runtime.h>

#define N_TOK 2048
#define DMODEL 1024
#define NH 16
#define NKV 4
#define HDIM 64
#define SCALE_LOG2E 0.1803368801111204f  // (1/8) * log2(e)

typedef __attribute__((ext_vector_type(8))) short short8;
typedef __attribute__((ext_vector_type(4))) float f32x4;
typedef unsigned short u16;
typedef unsigned int u32;

__device__ __forceinline__ u16 f2bf(float x) {
    u32 u = __float_as_uint(x);
    u += 0x7FFF + ((u >> 16) & 1);   // round-to-nearest-even
    return (u16)(u >> 16);
}
__device__ __forceinline__ u16 f2bf_trunc(float x) {
    return (u16)(__float_as_uint(x) >> 16);
}
__device__ __forceinline__ u32 pack2(float a, float b) {
    return (u32)f2bf(a) | ((u32)f2bf(b) << 16);
}

// ---------------------------------------------------------------------------
// prep: z=0..3 transpose W (K x NC) -> Wt (NC x K) bf16; z=4 convert x -> bf16
// ---------------------------------------------------------------------------
__global__ __launch_bounds__(256) void prep(
    const float* __restrict__ Wq, const float* __restrict__ Wk,
    const float* __restrict__ Wv, const float* __restrict__ Wo,
    const float* __restrict__ x,
    u16* __restrict__ Wqt, u16* __restrict__ Wkt, u16* __restrict__ Wvt,
    u16* __restrict__ Wot, u16* __restrict__ xb)
{
    const int z = blockIdx.z;
    const int t = threadIdx.x;
    if (z == 4) {
        size_t base = ((size_t)(blockIdx.y * 16 + blockIdx.x)) * 8192;
#pragma unroll
        for (int i = 0; i < 8; ++i) {
            float4 v = *(const float4*)(x + base + i * 1024 + t * 4);
            uint2 p; p.x = pack2(v.x, v.y); p.y = pack2(v.z, v.w);
            *(uint2*)(xb + base + i * 1024 + t * 4) = p;
        }
        return;
    }
    const float* W; u16* Wt; int NC;
    if      (z == 0) { W = Wq; Wt = Wqt; NC = 1024; }
    else if (z == 1) { W = Wk; Wt = Wkt; NC = 256; }
    else if (z == 2) { W = Wv; Wt = Wvt; NC = 256; }
    else             { W = Wo; Wt = Wot; NC = 1024; }
    const int n0 = blockIdx.x * 64;
    if (n0 >= NC) return;
    const int k0 = blockIdx.y * 64;
    __shared__ float T[64][68];
    const int row = t >> 2, cs = (t & 3) * 16;
#pragma unroll
    for (int i = 0; i < 4; ++i)
        *(float4*)&T[row][cs + i * 4] =
            *(const float4*)(W + (size_t)(k0 + row) * NC + n0 + cs + i * 4);
    __syncthreads();
    const int nl = t >> 2, ks = (t & 3) * 16;
    u32 pk[8];
#pragma unroll
    for (int i = 0; i < 8; ++i)
        pk[i] = pack2(T[ks + 2 * i][nl], T[ks + 2 * i + 1][nl]);
    u16* dst = Wt + (size_t)(n0 + nl) * DMODEL + k0 + ks;
    uint4 w0; w0.x = pk[0]; w0.y = pk[1]; w0.z = pk[2]; w0.w = pk[3];
    uint4 w1; w1.x = pk[4]; w1.y = pk[5]; w1.z = pk[6]; w1.w = pk[7];
    *(uint4*)(dst) = w0;
    *(uint4*)(dst + 8) = w1;
}

// ---------------------------------------------------------------------------
// QKV GEMM: tile 128x128, BK=32, 4 waves of 64x64 (m97 structure).
// grid (16,12): by<8 -> Q (rope, x SCALE_LOG2E); 8,9 -> K (rope);
// 10,11 -> V in FRAGMENT-PACKED layout FV for direct B-frag global loads:
//   FV[((((g*32+kt)*4+dt)*2+c)*64 + quad*16 + l15)*8 + j]
//     = V[token = kt*64 + c*32 + quad*8 + j][d = dt*16 + l15]  (per kv-head g)
// ---------------------------------------------------------------------------
__global__ __launch_bounds__(256, 2) void gemm_qkv(
    const u16* __restrict__ A,
    const u16* __restrict__ B0, const u16* __restrict__ B1, const u16* __restrict__ B2,
    u16* __restrict__ D0, u16* __restrict__ D1, u16* __restrict__ FVout,
    const float* __restrict__ fc, const float* __restrict__ fs)
{
    __shared__ u16 As[128][40];
    __shared__ u16 Bs[128][40];
    const int t = threadIdx.x;
    const int m0 = blockIdx.x * 128;
    const int by = blockIdx.y;

    const u16* Bt; int nl0, ep;           // ep: 1 rope bf16, 2 FV
    u16* dbf = nullptr; int dstride = 0; float epsc = 1.f;
    if (by < 8)       { Bt = B0; nl0 = by * 128;        dbf = D0; ep = 1; dstride = 1024;
                        epsc = SCALE_LOG2E; }
    else if (by < 10) { Bt = B1; nl0 = (by - 8) * 128;  dbf = D1; ep = 1; dstride = 256; }
    else              { Bt = B2; nl0 = (by - 10) * 128; ep = 2; }

    const int w = t >> 6, lane = t & 63;
    const int quad = lane >> 4, l15 = lane & 15;
    const int wm = (w >> 1) * 64, wn = (w & 1) * 64;
    const int srow = t >> 1, sk = (t & 1) * 16;

    const u16* Ap = A + (size_t)(m0 + srow) * DMODEL + sk;
    const u16* Bp = Bt + (size_t)(nl0 + srow) * DMODEL + sk;

    f32x4 acc[4][4];
#pragma unroll
    for (int i = 0; i < 4; ++i)
#pragma unroll
        for (int j = 0; j < 4; ++j) acc[i][j] = {0.f, 0.f, 0.f, 0.f};

    uint4 ar0 = *(const uint4*)(Ap);
    uint4 ar1 = *(const uint4*)(Ap + 8);
    uint4 br0 = *(const uint4*)(Bp);
    uint4 br1 = *(const uint4*)(Bp + 8);

    for (int k0 = 0; k0 < DMODEL; k0 += 32) {
        __syncthreads();
        *(uint4*)&As[srow][sk]     = ar0;
        *(uint4*)&As[srow][sk + 8] = ar1;
        *(uint4*)&Bs[srow][sk]     = br0;
        *(uint4*)&Bs[srow][sk + 8] = br1;
        __syncthreads();
        if (k0 + 32 < DMODEL) {
            ar0 = *(const uint4*)(Ap + k0 + 32);
            ar1 = *(const uint4*)(Ap + k0 + 40);
            br0 = *(const uint4*)(Bp + k0 + 32);
            br1 = *(const uint4*)(Bp + k0 + 40);
        }
        short8 af[4], bf[4];
#pragma unroll
        for (int i = 0; i < 4; ++i)
            af[i] = *(const short8*)&As[wm + i * 16 + l15][quad * 8];
#pragma unroll
        for (int j = 0; j < 4; ++j)
            bf[j] = *(const short8*)&Bs[wn + j * 16 + l15][quad * 8];
#pragma unroll
        for (int i = 0; i < 4; ++i)
#pragma unroll
            for (int j = 0; j < 4; ++j)
                acc[i][j] = __builtin_amdgcn_mfma_f32_16x16x32_bf16(af[i], bf[j], acc[i][j], 0, 0, 0);
    }

#pragma unroll
    for (int i = 0; i < 4; ++i)
#pragma unroll
        for (int j = 0; j < 4; ++j) {
            const int cl = nl0 + wn + j * 16 + l15;
#pragma unroll
            for (int r4 = 0; r4 < 4; ++r4) {
                const int r = m0 + wm + i * 16 + quad * 4 + r4;
                float own = acc[i][j][r4];
                if (ep == 1) {
                    float other = __shfl_xor(own, 1, 64);
                    const int p = (cl & 63) >> 1;
                    const float c = fc[r * 32 + p] * epsc, s = fs[r * 32 + p] * epsc;
                    float outv = ((cl & 1) == 0) ? (own * c - other * s)
                                                 : (other * s + own * c);
                    dbf[(size_t)r * dstride + cl] = f2bf(outv);
                } else {
                    const int g = cl >> 6, d = cl & 63;
                    const int dt = d >> 4, l15v = d & 15;
                    const int kt = r >> 6, klo = r & 63;
                    const int c = klo >> 5, k5 = klo & 31;
                    const int qd = k5 >> 3, jv = k5 & 7;
                    size_t idx = ((((size_t)(g * 32 + kt) * 4 + dt) * 2 + c) * 64
                                  + qd * 16 + l15v) * 8 + jv;
                    FVout[idx] = f2bf(own);
                }
            }
        }
}

// ---------------------------------------------------------------------------
// Output GEMM: tile 64x128, BK=32, 4 waves of 32x64, fp32 out. grid (32,8).
// ---------------------------------------------------------------------------
__global__ __launch_bounds__(256, 2) void gemm_out(
    const u16* __restrict__ A, const u16* __restrict__ Bt, float* __restrict__ Dout)
{
    __shared__ u16 As[64][40];
    __shared__ u16 Bs[128][40];
    const int t = threadIdx.x;
    const int m0 = blockIdx.x * 64;
    const int nl0 = blockIdx.y * 128;

    const int w = t >> 6, lane = t & 63;
    const int quad = lane >> 4, l15 = lane & 15;
    const int wm = (w >> 1) * 32, wn = (w & 1) * 64;
    const int arow = t >> 2, acol = (t & 3) * 8;
    const int brow = t >> 1, bcol = (t & 1) * 16;

    const u16* Ap = A + (size_t)(m0 + arow) * DMODEL + acol;
    const u16* Bp = Bt + (size_t)(nl0 + brow) * DMODEL + bcol;

    f32x4 acc[2][4];
#pragma unroll
    for (int i = 0; i < 2; ++i)
#pragma unroll
        for (int j = 0; j < 4; ++j) acc[i][j] = {0.f, 0.f, 0.f, 0.f};

    uint4 ar  = *(const uint4*)(Ap);
    uint4 br0 = *(const uint4*)(Bp);
    uint4 br1 = *(const uint4*)(Bp + 8);

    for (int k0 = 0; k0 < DMODEL; k0 += 32) {
        __syncthreads();
        *(uint4*)&As[arow][acol]     = ar;
        *(uint4*)&Bs[brow][bcol]     = br0;
        *(uint4*)&Bs[brow][bcol + 8] = br1;
        __syncthreads();
        if (k0 + 32 < DMODEL) {
            ar  = *(const uint4*)(Ap + k0 + 32);
            br0 = *(const uint4*)(Bp + k0 + 32);
            br1 = *(const uint4*)(Bp + k0 + 40);
        }
        short8 af[2], bf[4];
#pragma unroll
        for (int i = 0; i < 2; ++i)
            af[i] = *(const short8*)&As[wm + i * 16 + l15][quad * 8];
#pragma unroll
        for (int j = 0; j < 4; ++j)
            bf[j] = *(const short8*)&Bs[wn + j * 16 + l15][quad * 8];
#pragma unroll
        for (int i = 0; i < 2; ++i)
#pragma unroll
            for (int j = 0; j < 4; ++j)
                acc[i][j] = __builtin_amdgcn_mfma_f32_16x16x32_bf16(af[i], bf[j], acc[i][j], 0, 0, 0);
    }

#pragma unroll
    for (int i = 0; i < 2; ++i)
#pragma unroll
        for (int j = 0; j < 4; ++j) {
            const int cl = nl0 + wn + j * 16 + l15;
#pragma unroll
            for (int r4 = 0; r4 < 4; ++r4) {
                const int r = m0 + wm + i * 16 + quad * 4 + r4;
                Dout[(size_t)r * 1024 + cl] = acc[i][j][r4];
            }
        }
}

// ---------------------------------------------------------------------------
// MFMA flash attention. 256 thr / 4 waves, 64 q-rows per block (16/wave),
// grid (32,16)=512 (2 blocks/CU, 8 waves/CU). No-max softmax.
// K: double-buffered LDS staging, ONE barrier/iter. V: B-frags loaded DIRECT
// from global fragment-packed FV (L2-hot, coalesced dwordx4), prefetched one
// iter ahead. P: truncating bf16, wave-private LDS round-trip (lgkm only).
// ---------------------------------------------------------------------------
__global__ __launch_bounds__(256, 2) void attn(
    const u16* __restrict__ Qb, const u16* __restrict__ Kb,
    const u16* __restrict__ FV, u16* __restrict__ Ob)
{
    __shared__ u16 Ks[2][64][72];   // [buf][key][d]
    __shared__ u16 Ps[4][16][68];   // [wave][qrow][key]

    const int t = threadIdx.x;
    const int n0 = blockIdx.x * 64;
    const int h = blockIdx.y, kvh = h >> 2;
    const int w = t >> 6, lane = t & 63;
    const int quad = lane >> 4, l15 = lane & 15;
    const int srow = t >> 2, ssel = (t & 3) * 16;

    // Q A-frags (loop-invariant, registers)
    const u16* qp = Qb + (size_t)(n0 + w * 16 + l15) * (NH * HDIM) + h * HDIM + quad * 8;
    const short8 aq0 = *(const short8*)qp;
    const short8 aq1 = *(const short8*)(qp + 32);

    // K staging base (coalesced rows)
    const u16* kbase = Kb + (size_t)srow * (NKV * HDIM) + kvh * HDIM + ssel;
    // V frag base for this kv-head: frag (kt,dt,c) at fvb + kt*4096 + (dt*2+c)*512 + lane*8
    const u16* fvb = FV + ((size_t)kvh * 32 * 4096) + (size_t)lane * 8;

    f32x4 o[4];
    float l_acc[4];
#pragma unroll
    for (int i = 0; i < 4; ++i) { o[i] = {0.f, 0.f, 0.f, 0.f}; l_acc[i] = 0.f; }

    // prologue: K tile 0 -> buf 0; V frags for tile 0 -> regs
    *(uint4*)&Ks[0][srow][ssel]     = *(const uint4*)(kbase);
    *(uint4*)&Ks[0][srow][ssel + 8] = *(const uint4*)(kbase + 8);
    short8 vf[4][2];
#pragma unroll
    for (int dt = 0; dt < 4; ++dt)
#pragma unroll
        for (int c = 0; c < 2; ++c)
            vf[dt][c] = *(const short8*)(fvb + (dt * 2 + c) * 512);
    __syncthreads();

    const int NT = N_TOK / 64;
    for (int kt = 0; kt < NT; ++kt) {
        const int cur = kt & 1, nxt = cur ^ 1;
        const int ktn = (kt + 1) & (NT - 1);   // wraps on last iter (dead data)
        // prefetch next K tile to regs
        uint4 kr0 = *(const uint4*)(kbase + (size_t)(ktn * 64) * (NKV * HDIM));
        uint4 kr1 = *(const uint4*)(kbase + (size_t)(ktn * 64) * (NKV * HDIM) + 8);
        // prefetch next V frags to regs
        short8 vfn[4][2];
#pragma unroll
        for (int dt = 0; dt < 4; ++dt)
#pragma unroll
            for (int c = 0; c < 2; ++c)
                vfn[dt][c] = *(const short8*)(fvb + (size_t)ktn * 4096 + (dt * 2 + c) * 512);

        // ---- S = Q K^T (16 q x 64 keys per wave) ----
        f32x4 s[4];
#pragma unroll
        for (int nt = 0; nt < 4; ++nt) {
            f32x4 z = {0.f, 0.f, 0.f, 0.f};
            short8 b0 = *(const short8*)&Ks[cur][nt * 16 + l15][quad * 8];
            short8 b1 = *(const short8*)&Ks[cur][nt * 16 + l15][quad * 8 + 32];
            z = __builtin_amdgcn_mfma_f32_16x16x32_bf16(aq0, b0, z, 0, 0, 0);
            z = __builtin_amdgcn_mfma_f32_16x16x32_bf16(aq1, b1, z, 0, 0, 0);
            s[nt] = z;
        }
        // ---- p = exp2(s); per-lane row-sum; P -> wave-private LDS (trunc) ----
#pragma unroll
        for (int nt = 0; nt < 4; ++nt)
#pragma unroll
            for (int r = 0; r < 4; ++r) {
                float p = __builtin_amdgcn_exp2f(s[nt][r]);
                l_acc[r] += p;
                Ps[w][quad * 4 + r][nt * 16 + l15] = f2bf_trunc(p);
            }
        const short8 ap0 = *(const short8*)&Ps[w][l15][quad * 8];
        const short8 ap1 = *(const short8*)&Ps[w][l15][quad * 8 + 32];
        // ---- O += P V (V frags from registers, loaded last iter) ----
#pragma unroll
        for (int dt = 0; dt < 4; ++dt) {
            o[dt] = __builtin_amdgcn_mfma_f32_16x16x32_bf16(ap0, vf[dt][0], o[dt], 0, 0, 0);
            o[dt] = __builtin_amdgcn_mfma_f32_16x16x32_bf16(ap1, vf[dt][1], o[dt], 0, 0, 0);
        }
        // rotate V frags
#pragma unroll
        for (int dt = 0; dt < 4; ++dt)
#pragma unroll
            for (int c = 0; c < 2; ++c) vf[dt][c] = vfn[dt][c];
        // ---- stage next K tile; single barrier ----
        *(uint4*)&Ks[nxt][srow][ssel]     = kr0;
        *(uint4*)&Ks[nxt][srow][ssel + 8] = kr1;
        __syncthreads();
    }

    // epilogue: reduce l across 16 lanes of each quad, normalize, store
    float linv[4];
#pragma unroll
    for (int r = 0; r < 4; ++r) {
        float lv = l_acc[r];
#pragma unroll
        for (int d = 1; d < 16; d <<= 1) lv += __shfl_xor(lv, d, 64);
        linv[r] = 1.f / lv;
    }
#pragma unroll
    for (int dt = 0; dt < 4; ++dt)
#pragma unroll
        for (int r = 0; r < 4; ++r) {
            const int qrow = n0 + w * 16 + quad * 4 + r;
            const int col = h * HDIM + dt * 16 + l15;
            Ob[(size_t)qrow * (NH * HDIM) + col] = f2bf(o[dt][r] * linv[r]);
        }
}

// ---------------------------------------------------------------------------
extern "C" void kernel_launch(void* const* d_in, const int* in_sizes, int n_in,
                              void* d_out, int out_size, void* d_ws, size_t ws_size,
                              hipStream_t stream) {
    const float* x  = (const float*)d_in[0];
    const float* fc = (const float*)d_in[1];
    const float* fs = (const float*)d_in[2];
    const float* Wq = (const float*)d_in[3];
    const float* Wk = (const float*)d_in[4];
    const float* Wv = (const float*)d_in[5];
    const float* Wo = (const float*)d_in[6];
    float* out = (float*)d_out;

    u16* ws  = (u16*)d_ws;
    u16* xb  = ws;                         // 2048*1024
    u16* Wqt = xb  + (size_t)2048 * 1024;  // 1024*1024
    u16* Wkt = Wqt + (size_t)1024 * 1024;  // 256*1024
    u16* Wvt = Wkt + (size_t)256 * 1024;   // 256*1024
    u16* Wot = Wvt + (size_t)256 * 1024;   // 1024*1024
    u16* qb  = Wot + (size_t)1024 * 1024;  // 2048*1024
    u16* kb  = qb  + (size_t)2048 * 1024;  // 2048*256
    u16* fv  = kb  + (size_t)2048 * 256;   // 256*2048 (fragment-packed V)
    u16* aob = fv  + (size_t)256 * 2048;   // 2048*1024

    prep<<<dim3(16, 16, 5), dim3(256), 0, stream>>>(Wq, Wk, Wv, Wo, x,
                                                    Wqt, Wkt, Wvt, Wot, xb);
    gemm_qkv<<<dim3(16, 12), dim3(256), 0, stream>>>(xb, Wqt, Wkt, Wvt,
                                                     qb, kb, fv, fc, fs);
    attn<<<dim3(32, 16), dim3(256), 0, stream>>>(qb, kb, fv, aob);
    gemm_out<<<dim3(32, 8), dim3(256), 0, stream>>>(aob, Wot, out);
}